// Round 3
// baseline (103.044 us; speedup 1.0000x reference)
//
#include <hip/hip_runtime.h>
#include <hip/hip_bf16.h>

#define TD_B 512

typedef __bf16 bf16x8 __attribute__((ext_vector_type(8)));
typedef __bf16 bf16x4 __attribute__((ext_vector_type(4)));
typedef float  f32x4  __attribute__((ext_vector_type(4)));

#define MFMA(a, b, c) __builtin_amdgcn_mfma_f32_16x16x32_bf16((a), (b), (c), 0, 0, 0)

__device__ __forceinline__ float sigf(float x)  { return 1.0f / (1.0f + __expf(-x)); }
__device__ __forceinline__ float tanhf_(float x){ return 2.0f / (1.0f + __expf(-2.0f * x)) - 1.0f; }

extern "C" __global__ void __launch_bounds__(256, 2)
traj_disc_kernel(const float* __restrict__ x, const float* __restrict__ dmat,
                 const float* __restrict__ bmat, const float* __restrict__ hmat,
                 const float* __restrict__ mask,
                 const float* __restrict__ emb_w, const float* __restrict__ emb_b,
                 const float* __restrict__ w_ih, const float* __restrict__ w_hh,
                 const float* __restrict__ b_ih, const float* __restrict__ b_hh,
                 const float* __restrict__ e2a_w, const float* __restrict__ e2a_b,
                 const float* __restrict__ dom,
                 const float* __restrict__ sp_w, const float* __restrict__ sp_b,
                 const float* __restrict__ a2e_w, const float* __restrict__ a2e_b,
                 const float* __restrict__ w1, const float* __restrict__ b1,
                 const float* __restrict__ w2, const float* __restrict__ b2,
                 const float* __restrict__ w3, const float* __restrict__ b3,
                 float* __restrict__ out)
{
    const int b   = blockIdx.x;
    const int tid = threadIdx.x;
    const int lane = tid & 63;
    const int w    = tid >> 6;     // wave 0..3
    const int l15  = lane & 15;
    const int lg   = lane >> 4;    // 0..3

    __shared__ __bf16 sAin[32][80];              // 0-15 xe | 16-47 h | 48-63 zero | pad
    __shared__ __align__(16) char sGateBuf[17408]; // f32 [32][132] gates; aliased by z1/z2 bf16 tail
    __shared__ __bf16 sHl[32][40];
    __shared__ __bf16 sWN[32][40];
    __shared__ float  sMaskT[20][36];
    __shared__ float  sDom[144];
    __shared__ __bf16 sPAv [4][32][72];          // wave-private: 0-31 ha | 32-63 att
    __shared__ __bf16 sHaTv[4][32][40];          // wave-private: ha transposed
    __shared__ __bf16 sEmbv[4][32][40];          // wave-private

    float (*sGate)[132] = (float (*)[132])sGateBuf;
    __bf16 (*sPA)[72]  = sPAv[w];
    __bf16 (*sHaT)[40] = sHaTv[w];
    __bf16 (*sEmb)[40] = sEmbv[w];

    // ================= P0: one-time staging =================
    for (int idx = tid; idx < 32 * 80; idx += 256) (&sAin[0][0])[idx] = (__bf16)0.0f;
    for (int idx = tid; idx < 640; idx += 256) {
        int tt = idx >> 5, n = idx & 31;
        sMaskT[tt][n] = mask[(b * 32 + n) * 20 + tt];
    }
    if (tid < 144) sDom[tid] = dom[tid];

    // per-thread hoisted constants
    const int i0 = tid >> 3, p0 = tid & 7;       // wmat row / quad ; also xe row / col-pair
    const int hI = tid & 31, nb = tid >> 5;      // cell-update map
    const float ewa0 = emb_w[2 * p0],      ewa1 = emb_w[2 * p0 + 1];
    const float ewb0 = emb_w[16 + 2 * p0], ewb1 = emb_w[16 + 2 * p0 + 1];
    const float eb0  = emb_b[2 * p0],      eb1  = emb_b[2 * p0 + 1];
    float4 bb4;
    bb4.x = b_ih[hI] + b_hh[hI];
    bb4.y = b_ih[32 + hI] + b_hh[32 + hI];
    bb4.z = b_ih[64 + hI] + b_hh[64 + hI];
    bb4.w = b_ih[96 + hI] + b_hh[96 + hI];
    const float bE[2] = { e2a_b[l15], e2a_b[16 + l15] };
    const float bS[2] = { sp_b[l15],  sp_b[16 + l15] };
    const float bA[2] = { a2e_b[l15], a2e_b[16 + l15] };

    // gates B-frags (cols split across waves), gate-interleaved col c=4h+g
    bf16x8 Bg[2][2];
    #pragma unroll
    for (int kt = 0; kt < 2; ++kt)
        #pragma unroll
        for (int ntp = 0; ntp < 2; ++ntp) {
            int c = (2 * w + ntp) * 16 + l15;
            int cg = (c & 3) * 32 + (c >> 2);
            #pragma unroll
            for (int j = 0; j < 8; ++j) {
                int row = kt * 32 + lg * 8 + j;
                float v = (row < 16) ? w_ih[row * 128 + cg]
                         : (row < 48) ? w_hh[(row - 16) * 128 + cg] : 0.0f;
                Bg[kt][ntp][j] = (__bf16)v;
            }
        }
    // full-coverage frags for wave-private phases
    bf16x8 Be2aF[2], Ba2eF[2], BspF[2][2];
    #pragma unroll
    for (int nt2 = 0; nt2 < 2; ++nt2) {
        int c2 = nt2 * 16 + l15;
        #pragma unroll
        for (int j = 0; j < 8; ++j) {
            int row = lg * 8 + j;
            Be2aF[nt2][j] = (__bf16)e2a_w[row * 32 + c2];
            Ba2eF[nt2][j] = (__bf16)a2e_w[row * 32 + c2];
        }
        #pragma unroll
        for (int kt = 0; kt < 2; ++kt)
            #pragma unroll
            for (int j = 0; j < 8; ++j)
                BspF[kt][nt2][j] = (__bf16)sp_w[(kt * 32 + lg * 8 + j) * 32 + c2];
    }

    float cst[4] = {0.f, 0.f, 0.f, 0.f};
    f32x4 accZ[2][2] = {};
    bf16x8 Bw1cur[2];

    // prefetch t=0 inputs into registers
    float4 pdv, pbv, phv; float px0, px1;
    {
        int base = ((b * 32 + i0) * 20 + 0) * 32 + 4 * p0;
        pdv = *(const float4*)(dmat + base);
        pbv = *(const float4*)(bmat + base);
        phv = *(const float4*)(hmat + base);
        int xb = ((b * 32 + i0) * 20 + 0) * 2;
        px0 = x[xb]; px1 = x[xb + 1];
    }
    __syncthreads();

    #pragma unroll 1
    for (int t = 0; t < 20; ++t) {
        // ===== P1: wmat+normalize in registers, xe, prefetch t+1 =====
        float4 dv = pdv, bv = pbv, hv = phv;
        float xx0 = px0, xx1 = px1;
        if (t < 19) {
            int base = ((b * 32 + i0) * 20 + (t + 1)) * 32 + 4 * p0;
            pdv = *(const float4*)(dmat + base);
            pbv = *(const float4*)(bmat + base);
            phv = *(const float4*)(hmat + base);
            int xb = ((b * 32 + i0) * 20 + (t + 1)) * 2;
            px0 = x[xb]; px1 = x[xb + 1];
        }
        float4 mj = *(const float4*)&sMaskT[t][4 * p0];
        float  mi = sMaskT[t][i0];
        float wq[4];
        #pragma unroll
        for (int q = 0; q < 4; ++q) {
            float bq = (&bv.x)[q], hq = (&hv.x)[q];
            int ib = (int)floorf(bq * (1.0f / 30.0f)); ib = ib < 0 ? 0 : (ib > 11 ? 11 : ib);
            int ih = (int)floorf(hq * (1.0f / 30.0f)); ih = ih < 0 ? 0 : (ih > 11 ? 11 : ih);
            float v = sDom[ib * 12 + ih] - (&dv.x)[q];
            v = v > 0.f ? v : 0.f;
            wq[q] = v * (&mj.x)[q];
        }
        float s = wq[0] + wq[1] + wq[2] + wq[3];
        s += __shfl_xor(s, 1); s += __shfl_xor(s, 2); s += __shfl_xor(s, 4);
        float inv = mi / (mi * s + 1e-8f);
        bf16x4 wn4;
        #pragma unroll
        for (int q = 0; q < 4; ++q) wn4[q] = (__bf16)(wq[q] * inv);
        // xe -> sAin cols 0-15
        sAin[i0][2 * p0]     = (__bf16)(xx0 * ewa0 + xx1 * ewb0 + eb0);
        sAin[i0][2 * p0 + 1] = (__bf16)(xx0 * ewa1 + xx1 * ewb1 + eb1);
        __syncthreads();                                   // B1

        // ===== P2: wN store + gates MFMA + online z1 =====
        *(bf16x4*)&sWN[i0][4 * p0] = wn4;
        #pragma unroll
        for (int mt = 0; mt < 2; ++mt) {
            bf16x8 a0 = *(const bf16x8*)&sAin[mt * 16 + l15][lg * 8];
            bf16x8 a1 = *(const bf16x8*)&sAin[mt * 16 + l15][32 + lg * 8];
            #pragma unroll
            for (int ntp = 0; ntp < 2; ++ntp) {
                f32x4 cc = {0.f, 0.f, 0.f, 0.f};
                cc = MFMA(a0, Bg[0][ntp], cc);
                cc = MFMA(a1, Bg[1][ntp], cc);
                int c = (2 * w + ntp) * 16 + l15;
                #pragma unroll
                for (int q = 0; q < 4; ++q)
                    sGate[mt * 16 + lg * 4 + q][c] = cc[q];
            }
        }
        if (t >= 1) {
            #pragma unroll
            for (int mt = 0; mt < 2; ++mt) {
                bf16x8 ah = *(const bf16x8*)&sAin[mt * 16 + l15][16 + lg * 8];
                #pragma unroll
                for (int ntp = 0; ntp < 2; ++ntp)
                    accZ[mt][ntp] = MFMA(ah, Bw1cur[ntp], accZ[mt][ntp]);
            }
        }
        #pragma unroll
        for (int ntp = 0; ntp < 2; ++ntp) {        // prefetch w1 rows t*32.. (used at t+1 / tail)
            int c = (2 * w + ntp) * 16 + l15;
            #pragma unroll
            for (int j = 0; j < 8; ++j)
                Bw1cur[ntp][j] = (__bf16)w1[(t * 32 + lg * 8 + j) * 128 + c];
        }
        __syncthreads();                                   // B2

        // ===== P3: LSTM cell (c in registers) =====
        #pragma unroll
        for (int r = 0; r < 4; ++r) {
            int n = nb + 8 * r;
            float4 gv = *(const float4*)&sGate[n][4 * hI];
            float gi = gv.x + bb4.x, gf = gv.y + bb4.y, gg = gv.z + bb4.z, go = gv.w + bb4.w;
            float cn = sigf(gf) * cst[r] + sigf(gi) * tanhf_(gg);
            cst[r] = cn;
            sHl[n][hI] = (__bf16)(sigf(go) * tanhf_(cn));
        }
        __syncthreads();                                   // B3

        // ===== P4-P7: wave-private redundant chain (no barriers) =====
        // P4: ha = hl @ e2a (+b) -> sPA[:,0:32] and sHaT
        f32x4 haC[2][2];
        #pragma unroll
        for (int mt2 = 0; mt2 < 2; ++mt2) {
            bf16x8 a = *(const bf16x8*)&sHl[mt2 * 16 + l15][lg * 8];
            #pragma unroll
            for (int nt2 = 0; nt2 < 2; ++nt2) {
                f32x4 cc = {0.f, 0.f, 0.f, 0.f};
                haC[mt2][nt2] = MFMA(a, Be2aF[nt2], cc);
            }
        }
        #pragma unroll
        for (int mt2 = 0; mt2 < 2; ++mt2)
            #pragma unroll
            for (int nt2 = 0; nt2 < 2; ++nt2) {
                bf16x4 tv;
                #pragma unroll
                for (int q = 0; q < 4; ++q) {
                    float v = haC[mt2][nt2][q] + bE[nt2];
                    sPA[mt2 * 16 + lg * 4 + q][nt2 * 16 + l15] = (__bf16)v;
                    tv[q] = (__bf16)v;
                }
                *(bf16x4*)&sHaT[nt2 * 16 + l15][mt2 * 16 + lg * 4] = tv;
            }
        // P5: att = wN @ ha -> sPA[:,32:64]
        #pragma unroll
        for (int mt2 = 0; mt2 < 2; ++mt2) {
            bf16x8 aW = *(const bf16x8*)&sWN[mt2 * 16 + l15][lg * 8];
            #pragma unroll
            for (int nt2 = 0; nt2 < 2; ++nt2) {
                bf16x8 bT = *(const bf16x8*)&sHaT[nt2 * 16 + l15][lg * 8];
                f32x4 cc = {0.f, 0.f, 0.f, 0.f};
                cc = MFMA(aW, bT, cc);
                #pragma unroll
                for (int q = 0; q < 4; ++q)
                    sPA[mt2 * 16 + lg * 4 + q][32 + nt2 * 16 + l15] = (__bf16)cc[q];
            }
        }
        // P6: emb = tanh([ha|att] @ sp + b)
        #pragma unroll
        for (int mt2 = 0; mt2 < 2; ++mt2) {
            bf16x8 a0 = *(const bf16x8*)&sPA[mt2 * 16 + l15][lg * 8];
            bf16x8 a1 = *(const bf16x8*)&sPA[mt2 * 16 + l15][32 + lg * 8];
            #pragma unroll
            for (int nt2 = 0; nt2 < 2; ++nt2) {
                f32x4 cc = {0.f, 0.f, 0.f, 0.f};
                cc = MFMA(a0, BspF[0][nt2], cc);
                cc = MFMA(a1, BspF[1][nt2], cc);
                #pragma unroll
                for (int q = 0; q < 4; ++q)
                    sEmb[mt2 * 16 + lg * 4 + q][nt2 * 16 + l15] = (__bf16)tanhf_(cc[q] + bS[nt2]);
            }
        }
        // P7: h_new = emb @ a2e + b -> sAin cols 16-47 (same-value write, all waves)
        #pragma unroll
        for (int mt2 = 0; mt2 < 2; ++mt2) {
            bf16x8 a = *(const bf16x8*)&sEmb[mt2 * 16 + l15][lg * 8];
            #pragma unroll
            for (int nt2 = 0; nt2 < 2; ++nt2) {
                f32x4 cc = {0.f, 0.f, 0.f, 0.f};
                cc = MFMA(a, Ba2eF[nt2], cc);
                #pragma unroll
                for (int q = 0; q < 4; ++q)
                    sAin[mt2 * 16 + lg * 4 + q][16 + nt2 * 16 + l15] = (__bf16)(cc[q] + bA[nt2]);
            }
        }
    }

    // ================= tail: final z1 accumulate (h_19, w1 rows 608-639) =================
    #pragma unroll
    for (int mt = 0; mt < 2; ++mt) {
        bf16x8 ah = *(const bf16x8*)&sAin[mt * 16 + l15][16 + lg * 8];
        #pragma unroll
        for (int ntp = 0; ntp < 2; ++ntp)
            accZ[mt][ntp] = MFMA(ah, Bw1cur[ntp], accZ[mt][ntp]);
    }
    __bf16* z1bf = (__bf16*)sGateBuf;           // [32][136]
    __bf16* z2bf = z1bf + 32 * 136;             // [32][136]
    #pragma unroll
    for (int mt = 0; mt < 2; ++mt)
        #pragma unroll
        for (int ntp = 0; ntp < 2; ++ntp) {
            int c = (2 * w + ntp) * 16 + l15;
            float bias = b1[c];
            #pragma unroll
            for (int q = 0; q < 4; ++q) {
                float v = accZ[mt][ntp][q] + bias;
                v = v > 0.f ? v : 0.2f * v;
                z1bf[(mt * 16 + lg * 4 + q) * 136 + c] = (__bf16)v;
            }
        }
    __syncthreads();

    // z2 = leaky(z1 @ w2 + b2), K=128
    {
        f32x4 c2[2][2] = {};
        #pragma unroll
        for (int kt = 0; kt < 4; ++kt) {
            bf16x8 a[2];
            #pragma unroll
            for (int mt = 0; mt < 2; ++mt)
                a[mt] = *(const bf16x8*)&z1bf[(mt * 16 + l15) * 136 + kt * 32 + lg * 8];
            bf16x8 bb[2];
            #pragma unroll
            for (int ntp = 0; ntp < 2; ++ntp) {
                int c = (2 * w + ntp) * 16 + l15;
                #pragma unroll
                for (int j = 0; j < 8; ++j)
                    bb[ntp][j] = (__bf16)w2[(kt * 32 + lg * 8 + j) * 128 + c];
            }
            #pragma unroll
            for (int mt = 0; mt < 2; ++mt)
                #pragma unroll
                for (int ntp = 0; ntp < 2; ++ntp)
                    c2[mt][ntp] = MFMA(a[mt], bb[ntp], c2[mt][ntp]);
        }
        #pragma unroll
        for (int mt = 0; mt < 2; ++mt)
            #pragma unroll
            for (int ntp = 0; ntp < 2; ++ntp) {
                int c = (2 * w + ntp) * 16 + l15;
                float bias = b2[c];
                #pragma unroll
                for (int q = 0; q < 4; ++q) {
                    float v = c2[mt][ntp][q] + bias;
                    v = v > 0.f ? v : 0.2f * v;
                    z2bf[(mt * 16 + lg * 4 + q) * 136 + c] = (__bf16)v;
                }
            }
    }
    __syncthreads();

    // z3 = sigmoid(z2 @ w3 + b3)
    {
        int n = tid >> 3, kg = tid & 7;
        bf16x8 v0 = *(const bf16x8*)&z2bf[n * 136 + kg * 16];
        bf16x8 v1 = *(const bf16x8*)&z2bf[n * 136 + kg * 16 + 8];
        float s = 0.f;
        #pragma unroll
        for (int j = 0; j < 8; ++j)
            s += (float)v0[j] * w3[kg * 16 + j] + (float)v1[j] * w3[kg * 16 + 8 + j];
        s += __shfl_xor(s, 1); s += __shfl_xor(s, 2); s += __shfl_xor(s, 4);
        if (kg == 0) out[b * 32 + n] = 1.0f / (1.0f + __expf(-(s + b3[0])));
    }
}

extern "C" void kernel_launch(void* const* d_in, const int* in_sizes, int n_in,
                              void* d_out, int out_size, void* d_ws, size_t ws_size,
                              hipStream_t stream) {
    (void)in_sizes; (void)n_in; (void)d_ws; (void)ws_size; (void)out_size;
    const float* x     = (const float*)d_in[0];
    const float* dmat  = (const float*)d_in[1];
    const float* bmat  = (const float*)d_in[2];
    const float* hmat  = (const float*)d_in[3];
    const float* mask  = (const float*)d_in[4];
    const float* emb_w = (const float*)d_in[5];
    const float* emb_b = (const float*)d_in[6];
    const float* w_ih  = (const float*)d_in[7];
    const float* w_hh  = (const float*)d_in[8];
    const float* b_ih  = (const float*)d_in[9];
    const float* b_hh  = (const float*)d_in[10];
    const float* e2a_w = (const float*)d_in[11];
    const float* e2a_b = (const float*)d_in[12];
    const float* dom   = (const float*)d_in[13];
    const float* sp_w  = (const float*)d_in[14];
    const float* sp_b  = (const float*)d_in[15];
    const float* a2e_w = (const float*)d_in[16];
    const float* a2e_b = (const float*)d_in[17];
    const float* w1    = (const float*)d_in[18];
    const float* b1    = (const float*)d_in[19];
    const float* w2    = (const float*)d_in[20];
    const float* b2    = (const float*)d_in[21];
    const float* w3    = (const float*)d_in[22];
    const float* b3    = (const float*)d_in[23];
    float* out = (float*)d_out;

    traj_disc_kernel<<<dim3(TD_B), dim3(256), 0, stream>>>(
        x, dmat, bmat, hmat, mask, emb_w, emb_b, w_ih, w_hh, b_ih, b_hh,
        e2a_w, e2a_b, dom, sp_w, sp_b, a2e_w, a2e_b,
        w1, b1, w2, b2, w3, b3, out);
}